// Round 6
// baseline (315.516 us; speedup 1.0000x reference)
//
#include <hip/hip_runtime.h>

// DarkChannel: cmin over C=3, then 15x15 min erosion, +inf border.
// Round 6: L1-bypass test. Evidence: HBM read rate asymptotes ~2.0 TB/s
// across R1/R3/R4/R5 regardless of structure -> per-CU L1 request
// concurrency (~24 lines ~ 3 wave-dwordx4 in flight) is the suspected cap.
// Staging loads -> __builtin_nontemporal_load (global_load ... nt, no L1
// alloc), output stores -> nontemporal. Stage LDS writes b128 -> 2x b64
// (R3 showed b128 = 4-way phased, 7M conflicts). Otherwise R5 structure:
// 4 x-tiles x 64 y-strips x 16 imgs = 4096 blocks, 4 blocks/CU, LDS 31.9 KB.

#define IMG_H 1024
#define IMG_W 1024
#define IMG_C 3
#define IMG_B 16
#define TY    16              // output rows per block
#define TX    256             // output cols per block
#define HALO  8
#define BW    (TX + 2*HALO)   // 272 staged cols
#define ROWS  (TY + 14)       // 30 staged rows
#define NCH   (BW / 4)        // 68 float4 chunks per row
#define NT    256
#define RAD   7

typedef float vf4 __attribute__((ext_vector_type(4)));

__device__ __forceinline__ vf4 min4v(vf4 a, vf4 b) {
    vf4 r;
    r.x = fminf(a.x, b.x); r.y = fminf(a.y, b.y);
    r.z = fminf(a.z, b.z); r.w = fminf(a.w, b.w);
    return r;
}

__global__ __launch_bounds__(NT, 4)
void DarkChannel_77713138254515_kernel(const float* __restrict__ img,
                                       float* __restrict__ out) {
    __shared__ float buf[ROWS][BW];          // 30*272*4 = 31.9 KB

    const int t  = threadIdx.x;
    const int x0 = blockIdx.x * TX;
    const int y0 = blockIdx.y * TY;
    const int b  = blockIdx.z;

    const size_t plane = (size_t)IMG_H * IMG_W;
    const float* imgb = img + (size_t)b * IMG_C * plane;
    float* outb = out + (size_t)b * plane;
    const float INF = __builtin_inff();

    // ---- stage: 30 rows x 68 chunks = 2040 independent tasks, nt loads ----
#pragma unroll
    for (int k = 0; k < 8; ++k) {
        int task = t + NT * k;
        if (task < ROWS * NCH) {
            int r  = task / NCH;             // constant div -> magic mul
            int ch = task - r * NCH;
            int y  = y0 - RAD + r;
            int gx = x0 - HALO + 4 * ch;     // 4-aligned
            bool ok = ((unsigned)y < IMG_H) & ((unsigned)gx <= IMG_W - 4);
            int yc  = min(max(y, 0), IMG_H - 1);
            int gxc = min(max(gx, 0), IMG_W - 4);
            const float* p0 = imgb + (size_t)yc * IMG_W + gxc;
            vf4 v0 = __builtin_nontemporal_load((const vf4*)(p0));
            vf4 v1 = __builtin_nontemporal_load((const vf4*)(p0 + plane));
            vf4 v2 = __builtin_nontemporal_load((const vf4*)(p0 + 2 * plane));
            vf4 v  = min4v(v0, min4v(v1, v2));
            if (!ok) { v.x = INF; v.y = INF; v.z = INF; v.w = INF; }
            // two b64 stores (2-way aliasing free; b128 was 4-way conflicted)
            *(float2*)&buf[r][4 * ch]     = make_float2(v.x, v.y);
            *(float2*)&buf[r][4 * ch + 2] = make_float2(v.z, v.w);
        }
    }
    __syncthreads();

    // ---- vertical: van Herk per column, in place (stride-1 b32) ----
    for (int c = t; c < BW; c += NT) {       // t, and 256+t for t<16
        float col[ROWS];
#pragma unroll
        for (int r = 0; r < ROWS; ++r) col[r] = buf[r][c];
        float S[15];                         // suffix over col[0..14]
        S[14] = col[14];
#pragma unroll
        for (int i = 13; i >= 0; --i) S[i] = fminf(col[i], S[i + 1]);
        buf[0][c] = S[0];
        float p = col[15];                   // prefix over col[15..29]
#pragma unroll
        for (int i = 1; i < 15; ++i) {
            buf[i][c] = fminf(S[i], p);
            p = fminf(p, col[15 + i]);
        }
        buf[15][c] = p;                      // min(col[15..29])
    }
    __syncthreads();

    // ---- horizontal: 16 rows x 64 chunks = 1024 tasks, 4/thread ----
#pragma unroll
    for (int k = 0; k < 4; ++k) {
        int task = t + NT * k;
        int r  = task >> 6;
        int ch = task & 63;
        const float* row = &buf[r][4 * ch];  // buf col 4ch <-> img col x0-8+4ch
        float2 P[10];
#pragma unroll
        for (int j = 0; j < 10; ++j) P[j] = *(const float2*)(row + 2 * j);
        float2 m2 = P[2];                    // core = min w[4..15] = P2..P7
#pragma unroll
        for (int j = 3; j <= 7; ++j) {
            m2.x = fminf(m2.x, P[j].x); m2.y = fminf(m2.y, P[j].y);
        }
        float core = fminf(m2.x, m2.y);
        vf4 o;
        o.x = fminf(core, fminf(P[0].y, fminf(P[1].x, P[1].y))); // w[1..15]
        o.y = fminf(core, fminf(P[1].x, fminf(P[1].y, P[8].x))); // w[2..16]
        o.z = fminf(core, fminf(P[1].y, fminf(P[8].x, P[8].y))); // w[3..17]
        o.w = fminf(core, fminf(P[8].x, fminf(P[8].y, P[9].x))); // w[4..18]
        __builtin_nontemporal_store(
            o, (vf4*)(outb + (size_t)(y0 + r) * IMG_W + x0 + 4 * ch));
    }
}

extern "C" void kernel_launch(void* const* d_in, const int* in_sizes, int n_in,
                              void* d_out, int out_size, void* d_ws, size_t ws_size,
                              hipStream_t stream) {
    const float* img = (const float*)d_in[0];
    float* out = (float*)d_out;

    dim3 grid(IMG_W / TX,   // 4
              IMG_H / TY,   // 64
              IMG_B);       // 16 -> 4096 blocks = 4 gens at 4 blocks/CU
    DarkChannel_77713138254515_kernel<<<grid, dim3(NT), 0, stream>>>(img, out);
}

// Round 7
// 306.660 us; speedup vs baseline: 1.0289x; 1.0289x over previous
//
#include <hip/hip_runtime.h>

// DarkChannel: cmin over C=3, then 15x15 min erosion, +inf border.
// Round 7: two-pass via d_ws (768 MiB per the harness poison fills), both
// passes BARRIER-FREE and LDS-FREE. Theory: R5's ~100us = ~6 TB/s burst
// delivery x 1.99x halo amplification x ~20% duty-cycle loss from the
// vmcnt(0) drain that __syncthreads forces between stage and compute.
//  pass1: thread <-> one scalar column, 64-row segment (halo 78/64=1.22x,
//         zero x-halo), A/B 15-reg van Herk, no LDS, no barriers, 1024
//         blocks = one generation. Writes vmin into ws rows padded to 1040
//         with +-8 INF pads (edge threads write pads).
//  pass2: thread <-> float4 output, 5 aligned float4 loads from padded row
//         (4/5 overlap = L1-hot), nt store. Pure streamer, 16k blocks.

#define IMG_H 1024
#define IMG_W 1024
#define IMG_C 3
#define IMG_B 16
#define SEG   64
#define PAD   8
#define PW    (IMG_W + 2*PAD)   // 1040 padded row width (4160 B, 16B-aligned)

typedef float vf4 __attribute__((ext_vector_type(4)));

// ---------------- pass 1: channel-min + vertical 15-min ----------------
__global__ __launch_bounds__(256)
void dark_pass1_vert(const float* __restrict__ img, float* __restrict__ ws) {
    const int t = threadIdx.x;
    const int g = blockIdx.x;             // x-group 0..3
    const int s = blockIdx.y;             // y-segment 0..15
    const int b = blockIdx.z;
    const int x = g * 256 + t;            // this thread's column
    const int base = s * SEG;

    const size_t plane = (size_t)IMG_H * IMG_W;
    const float* imgb = img + (size_t)b * IMG_C * plane;
    float* wsb = ws + (size_t)b * IMG_H * PW;
    const float INF = __builtin_inff();

    auto cmin = [&](int y) -> float {
        int yc = min(max(y, 0), IMG_H - 1);
        const float* p = imgb + (size_t)yc * IMG_W + x;
        float v = fminf(__builtin_nontemporal_load(p),
                  fminf(__builtin_nontemporal_load(p + plane),
                        __builtin_nontemporal_load(p + 2 * plane)));
        return ((unsigned)y < IMG_H) ? v : INF;
    };

    float A[15], B[15];
#pragma unroll
    for (int i = 0; i < 15; ++i) A[i] = cmin(base - 7 + i);   // rows base-7..+7

#pragma unroll
    for (int gg = 0; gg < 4; ++gg) {                // outputs base .. base+59
#pragma unroll
        for (int i = 0; i < 15; ++i) B[i] = cmin(base + 8 + 15 * gg + i);
#pragma unroll
        for (int i = 13; i >= 0; --i) A[i] = fminf(A[i], A[i + 1]);  // suffix
        wsb[(size_t)(base + 15 * gg) * PW + PAD + x] = A[0];
        float p = B[0];
#pragma unroll
        for (int j = 1; j < 15; ++j) {
            wsb[(size_t)(base + 15 * gg + j) * PW + PAD + x] = fminf(A[j], p);
            if (j < 14) p = fminf(p, B[j]);
        }
#pragma unroll
        for (int i = 0; i < 15; ++i) A[i] = B[i];
    }

    // tail outputs base+60..base+63 (A = rows base+53..base+67)
    float e1 = cmin(base + 68), e2 = cmin(base + 69), e3 = cmin(base + 70);
#pragma unroll
    for (int i = 13; i >= 0; --i) A[i] = fminf(A[i], A[i + 1]);      // suffix
    wsb[(size_t)(base + 60) * PW + PAD + x] = A[0];
    wsb[(size_t)(base + 61) * PW + PAD + x] = fminf(A[1], e1);
    wsb[(size_t)(base + 62) * PW + PAD + x] = fminf(A[2], fminf(e1, e2));
    wsb[(size_t)(base + 63) * PW + PAD + x] =
        fminf(A[3], fminf(e1, fminf(e2, e3)));

    // INF pads (ws is poisoned 0xAA = small NEGATIVE float -> must overwrite)
    if (g == 0 && t < PAD) {
#pragma unroll 4
        for (int j = 0; j < SEG; ++j)
            wsb[(size_t)(base + j) * PW + t] = INF;
    }
    if (g == 3 && t >= 256 - PAD) {
#pragma unroll 4
        for (int j = 0; j < SEG; ++j)
            wsb[(size_t)(base + j) * PW + PAD + IMG_W + (t - (256 - PAD))] = INF;
    }
}

// ---------------- pass 2: horizontal 15-min ----------------
__global__ __launch_bounds__(256)
void dark_pass2_horiz(const float* __restrict__ ws, float* __restrict__ out) {
    const int t = threadIdx.x;            // float4 chunk within row
    const int y = blockIdx.x;
    const int b = blockIdx.y;

    const float* row = ws + ((size_t)b * IMG_H + y) * PW + 4 * t;
    // f[k] = padded col 4t+k = img col 4t+k-8, k = 0..19; all 16B-aligned
    vf4 a = *(const vf4*)(row);
    vf4 bb = *(const vf4*)(row + 4);
    vf4 cc = *(const vf4*)(row + 8);
    vf4 dd = *(const vf4*)(row + 12);
    vf4 ee = *(const vf4*)(row + 16);

    // core = min f4..f15
    vf4 m;
    m.x = fminf(bb.x, fminf(cc.x, dd.x));
    m.y = fminf(bb.y, fminf(cc.y, dd.y));
    m.z = fminf(bb.z, fminf(cc.z, dd.z));
    m.w = fminf(bb.w, fminf(cc.w, dd.w));
    float core = fminf(fminf(m.x, m.y), fminf(m.z, m.w));

    vf4 o;
    o.x = fminf(core, fminf(a.y, fminf(a.z, a.w)));    // f1..f15
    o.y = fminf(core, fminf(a.z, fminf(a.w, ee.x)));   // f2..f16
    o.z = fminf(core, fminf(a.w, fminf(ee.x, ee.y)));  // f3..f17
    o.w = fminf(core, fminf(ee.x, fminf(ee.y, ee.z))); // f4..f18
    __builtin_nontemporal_store(
        o, (vf4*)(out + ((size_t)b * IMG_H + y) * IMG_W + 4 * t));
}

extern "C" void kernel_launch(void* const* d_in, const int* in_sizes, int n_in,
                              void* d_out, int out_size, void* d_ws, size_t ws_size,
                              hipStream_t stream) {
    const float* img = (const float*)d_in[0];
    float* out = (float*)d_out;
    float* ws  = (float*)d_ws;   // needs 16*1024*1040*4 = 68.2 MB (ws = 768 MiB)

    dim3 g1(4, IMG_H / SEG, IMG_B);       // 4 x-groups, 16 segments, 16 imgs
    dark_pass1_vert<<<g1, dim3(256), 0, stream>>>(img, ws);

    dim3 g2(IMG_H, IMG_B);                // one block per output row
    dark_pass2_horiz<<<g2, dim3(256), 0, stream>>>(ws, out);
}